// Round 6
// baseline (221.174 us; speedup 1.0000x reference)
//
#include <hip/hip_runtime.h>
#include <hip/hip_bf16.h>

// ---------- types ----------
typedef short bf16x8 __attribute__((ext_vector_type(8)));
typedef float f32x4 __attribute__((ext_vector_type(4)));

#define NB 4
#define C 256
#define HW 4096
#define NROWS (NB * HW)   // 16384
#define EPSF 1e-5f

// ---------- helpers ----------
__device__ __forceinline__ unsigned short f2bf(float f) {
    unsigned int u = __float_as_uint(f);
    unsigned int r = u + 0x7fffu + ((u >> 16) & 1u);
    return (unsigned short)(r >> 16);
}
__device__ __forceinline__ float bf2f(unsigned int h) {
    return __uint_as_float(h << 16);
}
__device__ __forceinline__ void unpack8(uint4 u, float* v) {
    unsigned int w0 = u.x, w1 = u.y, w2 = u.z, w3 = u.w;
    v[0] = bf2f(w0 & 0xffffu); v[1] = bf2f(w0 >> 16);
    v[2] = bf2f(w1 & 0xffffu); v[3] = bf2f(w1 >> 16);
    v[4] = bf2f(w2 & 0xffffu); v[5] = bf2f(w2 >> 16);
    v[6] = bf2f(w3 & 0xffffu); v[7] = bf2f(w3 >> 16);
}
__device__ __forceinline__ float waveReduceSum(float v) {
    for (int off = 32; off > 0; off >>= 1) v += __shfl_xor(v, off);
    return v;
}
// async global->LDS 16B copy; lds ptr must be wave-uniform-base + lane*16
typedef __attribute__((address_space(1))) const unsigned int glb_cu;
typedef __attribute__((address_space(3))) unsigned int lds_u;
__device__ __forceinline__ void async_copy16(const unsigned short* g, unsigned short* l) {
    __builtin_amdgcn_global_load_lds((glb_cu*)g, (lds_u*)l, 16, 0, 0);
}

// ---------- K1: per-channel mean of y (+ zero accumulators for this iteration) ----------
__global__ __launch_bounds__(256) void mu_kernel(const float* __restrict__ y,
                                                 float* __restrict__ mu,
                                                 float* __restrict__ cxsum,
                                                 unsigned int* __restrict__ ticket) {
    int c = blockIdx.x;
    int tid = threadIdx.x;
    if (c == 0) {
        if (tid < NB) cxsum[tid] = 0.f;
        if (tid == NB) *ticket = 0u;
    }
    float s = 0.f;
    const float* base = y + (size_t)c * HW;
    for (int n = 0; n < NB; n++) {
        const float* bn = base + (size_t)n * C * HW;
        for (int i = tid; i < HW; i += 256) s += bn[i];
    }
    s = waveReduceSum(s);
    __shared__ float red[4];
    int lane = tid & 63, wave = tid >> 6;
    if (lane == 0) red[wave] = s;
    __syncthreads();
    if (tid == 0) mu[c] = (red[0] + red[1] + red[2] + red[3]) * (1.0f / 16384.0f);
}

// ---------- K2: center, L2-normalize over C, transpose to (n,p,c) bf16 ----------
#define TP 32
#define TSTRIDE 257
__global__ __launch_bounds__(256) void prep_kernel(const float* __restrict__ x,
                                                   const float* __restrict__ y,
                                                   const float* __restrict__ mu,
                                                   unsigned short* __restrict__ Xn,
                                                   unsigned short* __restrict__ Yn) {
    __shared__ float smu[C];
    __shared__ float tile[TP * TSTRIDE];
    __shared__ float red[8 * 32];
    __shared__ float invn[TP];
    int tid = threadIdx.x;
    smu[tid] = mu[tid];
    int blk = blockIdx.x;
    int n = blk >> 7;                // 128 blocks per batch
    int p0 = (blk & 127) * TP;
    int tp = tid & 31, cc = tid >> 5;
    __syncthreads();
    for (int pass = 0; pass < 2; pass++) {
        const float* in = pass ? y : x;
        unsigned short* out = pass ? Yn : Xn;
        const float* base = in + (size_t)n * C * HW + p0 + tp;
        float ssq = 0.f;
        for (int c = cc; c < C; c += 8) {
            float v = base[(size_t)c * HW] - smu[c];
            tile[tp * TSTRIDE + c] = v;
            ssq += v * v;
        }
        red[cc * 32 + tp] = ssq;
        __syncthreads();
        if (tid < 32) {
            float s = 0.f;
            for (int k = 0; k < 8; k++) s += red[k * 32 + tid];
            invn[tid] = rsqrtf(s);
        }
        __syncthreads();
        int c2 = (tid & 127) * 2;
        int pp = tid >> 7;
        for (int p = pp; p < TP; p += 2) {
            float inv = invn[p];
            unsigned short b0 = f2bf(tile[p * TSTRIDE + c2] * inv);
            unsigned short b1 = f2bf(tile[p * TSTRIDE + c2 + 1] * inv);
            unsigned int pack = (unsigned int)b0 | ((unsigned int)b1 << 16);
            ((unsigned int*)out)[(size_t)(n * HW + p0 + p) * (C / 2) + (c2 >> 1)] = pack;
        }
        __syncthreads();
    }
}

// ---------- K3: batched GEMM cos = Xn * Yn^T, bf16 out ----------
// PROVEN round-4 form (52 us for all n). Now launched PER-N with a single
// reused 33.5 MB Cos buffer so the producer->consumer distance is one
// dispatch and the working set stays L2/L3-resident.
#define EPSTRIDE 136
// stage quarter s (K elems [s*64, s*64+64)) of A,B into buffer b
#define STAGE(s, b)                                                            \
    do {                                                                       \
        unsigned short* lA = lds_us + (b) * 16384;                             \
        unsigned short* lB = lds_us + (b) * 16384 + 8192;                      \
        _Pragma("unroll")                                                      \
        for (int t = 0; t < 4; t++) {                                          \
            int slot = t * 256 + tid;                                          \
            int r = slot >> 3, cl = slot & 7;                                  \
            int c = (s) * 8 + (cl ^ (r & 7));                                  \
            async_copy16(Ab + (size_t)r * C + c * 8, lA + slot * 8);           \
        }                                                                      \
        _Pragma("unroll")                                                      \
        for (int t = 0; t < 4; t++) {                                          \
            int slot = t * 256 + tid;                                          \
            int r = slot >> 3, cl = slot & 7;                                  \
            int c = (s) * 8 + (cl ^ (r & 7));                                  \
            async_copy16(Bb + (size_t)r * C + c * 8, lB + slot * 8);           \
        }                                                                      \
    } while (0)

#define COMPUTE(b)                                                             \
    do {                                                                       \
        const unsigned short* lA = lds_us + (b) * 16384;                       \
        const unsigned short* lB = lds_us + (b) * 16384 + 8192;                \
        _Pragma("unroll")                                                      \
        for (int kkl = 0; kkl < 2; kkl++) {                                    \
            int cl4 = kkl * 4 + quad;                                          \
            int clp = cl4 ^ (mrow & 7);                                        \
            bf16x8 af[4], bfr[4];                                              \
            _Pragma("unroll")                                                  \
            for (int i = 0; i < 4; i++) {                                      \
                af[i]  = *(const bf16x8*)(lA + (wm + i * 16 + mrow) * 64 + clp * 8); \
                bfr[i] = *(const bf16x8*)(lB + (wn + i * 16 + mrow) * 64 + clp * 8); \
            }                                                                  \
            _Pragma("unroll")                                                  \
            for (int i = 0; i < 4; i++)                                        \
                _Pragma("unroll")                                              \
                for (int j = 0; j < 4; j++)                                    \
                    acc[i][j] = __builtin_amdgcn_mfma_f32_16x16x32_bf16(af[i], bfr[j], acc[i][j], 0, 0, 0); \
        }                                                                      \
    } while (0)

__global__ __launch_bounds__(256, 2) void gemm_cos(const unsigned short* __restrict__ Xn,
                                                   const unsigned short* __restrict__ Yn,
                                                   unsigned short* __restrict__ Cos,
                                                   int n) {
    __shared__ unsigned short lds_us[32768];   // 64 KB: buf0[A 16K|B 16K] buf1[A|B]
    int pBase = blockIdx.y * 128, qBase = blockIdx.x * 128;
    const unsigned short* Ab = Xn + ((size_t)n * HW + pBase) * C;
    const unsigned short* Bb = Yn + ((size_t)n * HW + qBase) * C;
    int tid = threadIdx.x, lane = tid & 63, wave = tid >> 6;
    int wm = (wave >> 1) * 64, wn = (wave & 1) * 64;
    int mrow = lane & 15, quad = lane >> 4;

    f32x4 acc[4][4];
#pragma unroll
    for (int i = 0; i < 4; i++)
#pragma unroll
        for (int j = 0; j < 4; j++) acc[i][j] = (f32x4){0.f, 0.f, 0.f, 0.f};

    // ---- prologue ----
    STAGE(0, 0);
    __syncthreads();                               // step0 landed (full drain)

    // ---- 2-phase steady state: issue next, compute current, drain ----
#pragma unroll
    for (int s = 0; s < 3; s++) {
        STAGE(s + 1, (s + 1) & 1);                 // issue next-step loads (other buffer)
        __builtin_amdgcn_sched_barrier(0);         // pin issue before MFMA cluster (compile-time only)
        COMPUTE(s & 1);                            // MFMA on current buffer
        __syncthreads();                           // full drain: next step landed, reads retired
    }

    // ---- tail ----
    COMPUTE(1);
    __syncthreads();   // before epilogue reuses LDS

    // ---- epilogue: transpose through LDS (bf16), coalesced dwordx4 stores ----
    unsigned short* epb = lds_us;  // 128 x EPSTRIDE bf16 = 34 KB
    int col = lane & 15, quad4 = quad * 4;
#pragma unroll
    for (int i = 0; i < 4; i++)
#pragma unroll
        for (int j = 0; j < 4; j++)
#pragma unroll
            for (int r = 0; r < 4; r++)
                epb[(wm + i * 16 + quad4 + r) * EPSTRIDE + wn + j * 16 + col] = f2bf(acc[i][j][r]);
    __syncthreads();
    unsigned short* Crow = Cos;    // single-n buffer (33.5 MB, reused across n)
#pragma unroll
    for (int it = 0; it < 8; it++) {
        int e = it * 2048 + tid * 8;
        int r = e >> 7, cg = e & 127;
        uint4 o = *(const uint4*)(epb + r * EPSTRIDE + cg);
        *(uint4*)(Crow + (size_t)(pBase + r) * HW + qBase + cg) = o;
    }
}

// ---------- K4: fused row stats + column logit-max (8 rows/block, reg-resident) ----------
// Per-n launch: reads the single-n Cos buffer written by the immediately
// preceding gemm_cos (L2/L3-hot), writes partial at the n-specific offset.
__global__ __launch_bounds__(256, 3) void rowcol(const unsigned short* __restrict__ Cos,
                                                 unsigned short* __restrict__ partial,
                                                 int n) {
    int chunk = blockIdx.x;   // 0..511, 8 rows each
    int tid = threadIdx.x, lane = tid & 63, wave = tid >> 6;
    const unsigned short* rowbase = Cos + ((size_t)chunk * 8) * HW;
    __shared__ float redm[8][4];
    __shared__ float sval[8][4];

    uint4 d[8][2];
#pragma unroll
    for (int r = 0; r < 8; r++) {
        const unsigned short* rp = rowbase + (size_t)r * HW;
        d[r][0] = *(const uint4*)(rp + tid * 8);
        d[r][1] = *(const uint4*)(rp + 2048 + tid * 8);
    }

    // phase 1: row maxes (batched butterfly)
    float m8[8];
#pragma unroll
    for (int r = 0; r < 8; r++) {
        float v[16];
        unpack8(d[r][0], v); unpack8(d[r][1], v + 8);
        float m = v[0];
#pragma unroll
        for (int k = 1; k < 16; k++) m = fmaxf(m, v[k]);
        m8[r] = m;
    }
#pragma unroll
    for (int off = 32; off > 0; off >>= 1)
#pragma unroll
        for (int r = 0; r < 8; r++) m8[r] = fmaxf(m8[r], __shfl_xor(m8[r], off));
    if (lane == 0)
#pragma unroll
        for (int r = 0; r < 8; r++) redm[r][wave] = m8[r];
    __syncthreads();

    float alpha[8], basec[8];
#pragma unroll
    for (int r = 0; r < 8; r++) {
        float M = fmaxf(fmaxf(redm[r][0], redm[r][1]), fmaxf(redm[r][2], redm[r][3]));
        alpha[r] = 2.0f / ((1.0f - M) + EPSF);
        basec[r] = 2.0f - alpha[r];
    }

    // phase 2: exp row-sums (batched butterfly)
    float s8[8];
#pragma unroll
    for (int r = 0; r < 8; r++) {
        float v[16];
        unpack8(d[r][0], v); unpack8(d[r][1], v + 8);
        float s = 0.f;
#pragma unroll
        for (int k = 0; k < 16; k++) s += __expf(fmaf(alpha[r], v[k], basec[r]));
        s8[r] = s;
    }
#pragma unroll
    for (int off = 32; off > 0; off >>= 1)
#pragma unroll
        for (int r = 0; r < 8; r++) s8[r] += __shfl_xor(s8[r], off);
    if (lane == 0)
#pragma unroll
        for (int r = 0; r < 8; r++) sval[r][wave] = s8[r];
    __syncthreads();

    // phase 3: beta + column logit-max
    float cmax[16];
#pragma unroll
    for (int k = 0; k < 16; k++) cmax[k] = -1e30f;
#pragma unroll
    for (int r = 0; r < 8; r++) {
        float S = sval[r][0] + sval[r][1] + sval[r][2] + sval[r][3];
        float beta = basec[r] - __logf(S);
        float v[16];
        unpack8(d[r][0], v); unpack8(d[r][1], v + 8);
#pragma unroll
        for (int k = 0; k < 16; k++) cmax[k] = fmaxf(cmax[k], fmaf(alpha[r], v[k], beta));
    }

    // store as bf16, packed uint4 (q = tid*8+k and 2048+tid*8+k)
    unsigned short* outp = partial + ((size_t)(n * 512 + chunk)) * HW;
    uint4 o0, o1;
    o0.x = (unsigned int)f2bf(cmax[0]) | ((unsigned int)f2bf(cmax[1]) << 16);
    o0.y = (unsigned int)f2bf(cmax[2]) | ((unsigned int)f2bf(cmax[3]) << 16);
    o0.z = (unsigned int)f2bf(cmax[4]) | ((unsigned int)f2bf(cmax[5]) << 16);
    o0.w = (unsigned int)f2bf(cmax[6]) | ((unsigned int)f2bf(cmax[7]) << 16);
    o1.x = (unsigned int)f2bf(cmax[8]) | ((unsigned int)f2bf(cmax[9]) << 16);
    o1.y = (unsigned int)f2bf(cmax[10]) | ((unsigned int)f2bf(cmax[11]) << 16);
    o1.z = (unsigned int)f2bf(cmax[12]) | ((unsigned int)f2bf(cmax[13]) << 16);
    o1.w = (unsigned int)f2bf(cmax[14]) | ((unsigned int)f2bf(cmax[15]) << 16);
    *(uint4*)(outp + tid * 8) = o0;
    *(uint4*)(outp + 2048 + tid * 8) = o1;
}

// ---------- K5: fused column max over all 512 chunks + exp + sum + final loss ----------
// grid (64, NB): block (g,n) owns 64 q-columns. Vectorized uint4 reads:
// thread (qo, cs) reads 8 q at chunk slice cs, 16 strided iterations.
// Max is order-independent; final 64-lane exp/sum path identical to before.
__global__ __launch_bounds__(256) void colred(const unsigned short* __restrict__ partial,
                                              float* __restrict__ cxsum,
                                              unsigned int* __restrict__ ticket,
                                              float* __restrict__ out) {
    int n = blockIdx.y, g = blockIdx.x;
    int tid = threadIdx.x;
    int qo = tid & 7;          // q-octet within the 64-q group
    int cs = tid >> 3;         // chunk slice 0..31
    const unsigned short* p = partial + ((size_t)(n * 512 + cs)) * HW + g * 64 + qo * 8;
    float mx[8];
#pragma unroll
    for (int k = 0; k < 8; k++) mx[k] = -1e30f;
#pragma unroll 4
    for (int c = cs; c < 512; c += 32) {
        uint4 u = *(const uint4*)p;
        float v[8];
        unpack8(u, v);
#pragma unroll
        for (int k = 0; k < 8; k++) mx[k] = fmaxf(mx[k], v[k]);
        p += (size_t)32 * HW;
    }
    __shared__ float sm[32][64];
#pragma unroll
    for (int k = 0; k < 8; k++) sm[cs][qo * 8 + k] = mx[k];
    __syncthreads();
    if (tid < 64) {
        float mm = -1e30f;
#pragma unroll
        for (int s = 0; s < 32; s++) mm = fmaxf(mm, sm[s][tid]);
        float sv = __expf(mm);
        sv = waveReduceSum(sv);
        if (tid == 0) {
            atomicAdd(&cxsum[n], sv);
            __threadfence();
            unsigned int old = atomicAdd(ticket, 1u);
            if (old == (unsigned int)(64 * NB - 1)) {
                __threadfence();
                float loss = 0.f;
                for (int b = 0; b < NB; b++) {
                    float csn = atomicAdd(&cxsum[b], 0.0f);  // device-scope read of final sum
                    loss += -logf(csn * (1.0f / 4096.0f) + EPSF);
                }
                out[0] = loss * 0.25f;
            }
        }
    }
}

// ---------- launch ----------
extern "C" void kernel_launch(void* const* d_in, const int* in_sizes, int n_in,
                              void* d_out, int out_size, void* d_ws, size_t ws_size,
                              hipStream_t stream) {
    const float* x = (const float*)d_in[0];
    const float* y = (const float*)d_in[1];
    float* out = (float*)d_out;
    char* ws = (char*)d_ws;

    float* mu               = (float*)(ws + 0);                   // 1 KiB
    float* cxsum            = (float*)(ws + 1024);                // 16 B
    unsigned int* ticket    = (unsigned int*)(ws + 1040);         // 4 B
    unsigned short* Xn      = (unsigned short*)(ws + 2097152);    // 8 MiB
    unsigned short* Yn      = (unsigned short*)(ws + 10485760);   // 8 MiB
    unsigned short* partial = (unsigned short*)(ws + 2097152);    // 16 MiB bf16 (aliases Xn+Yn? NO - now live同时)
    unsigned short* Cos     = (unsigned short*)(ws + 52428800);   // 33.5 MiB, reused for every n

    // NOTE: partial must NOT alias Xn/Yn anymore (gemm(n>0) still reads Xn/Yn
    // after rowcol(0) writes partial). Give partial its own region.
    partial = (unsigned short*)(ws + 18874368);                   // 16 MiB at 18 MiB offset

    mu_kernel<<<C, 256, 0, stream>>>(y, mu, cxsum, ticket);
    prep_kernel<<<NROWS / TP, 256, 0, stream>>>(x, y, mu, Xn, Yn);
    for (int n = 0; n < NB; n++) {
        gemm_cos<<<dim3(HW / 128, HW / 128), 256, 0, stream>>>(Xn, Yn, Cos, n);
        rowcol<<<512, 256, 0, stream>>>(Cos, partial, n);
    }
    colred<<<dim3(64, NB), 256, 0, stream>>>(partial, cxsum, ticket, out);
}

// Round 7
// 196.980 us; speedup vs baseline: 1.1228x; 1.1228x over previous
//
#include <hip/hip_runtime.h>
#include <hip/hip_bf16.h>

// ---------- types ----------
typedef short bf16x8 __attribute__((ext_vector_type(8)));
typedef float f32x4 __attribute__((ext_vector_type(4)));

#define NB 4
#define C 256
#define HW 4096
#define NROWS (NB * HW)   // 16384
#define EPSF 1e-5f

// ---------- helpers ----------
__device__ __forceinline__ unsigned short f2bf(float f) {
    unsigned int u = __float_as_uint(f);
    unsigned int r = u + 0x7fffu + ((u >> 16) & 1u);
    return (unsigned short)(r >> 16);
}
__device__ __forceinline__ float bf2f(unsigned int h) {
    return __uint_as_float(h << 16);
}
__device__ __forceinline__ void unpack8(uint4 u, float* v) {
    unsigned int w0 = u.x, w1 = u.y, w2 = u.z, w3 = u.w;
    v[0] = bf2f(w0 & 0xffffu); v[1] = bf2f(w0 >> 16);
    v[2] = bf2f(w1 & 0xffffu); v[3] = bf2f(w1 >> 16);
    v[4] = bf2f(w2 & 0xffffu); v[5] = bf2f(w2 >> 16);
    v[6] = bf2f(w3 & 0xffffu); v[7] = bf2f(w3 >> 16);
}
__device__ __forceinline__ float waveReduceSum(float v) {
    for (int off = 32; off > 0; off >>= 1) v += __shfl_xor(v, off);
    return v;
}
// async global->LDS 16B copy; lds ptr must be wave-uniform-base + lane*16
typedef __attribute__((address_space(1))) const unsigned int glb_cu;
typedef __attribute__((address_space(3))) unsigned int lds_u;
__device__ __forceinline__ void async_copy16(const unsigned short* g, unsigned short* l) {
    __builtin_amdgcn_global_load_lds((glb_cu*)g, (lds_u*)l, 16, 0, 0);
}

// ---------- K1: per-channel mean of y (+ zero accumulators for this iteration) ----------
__global__ __launch_bounds__(256) void mu_kernel(const float* __restrict__ y,
                                                 float* __restrict__ mu,
                                                 float* __restrict__ cxsum,
                                                 unsigned int* __restrict__ ticket) {
    int c = blockIdx.x;
    int tid = threadIdx.x;
    if (c == 0) {
        if (tid < NB) cxsum[tid] = 0.f;
        if (tid == NB) *ticket = 0u;
    }
    float s = 0.f;
    const float* base = y + (size_t)c * HW;
    for (int n = 0; n < NB; n++) {
        const float* bn = base + (size_t)n * C * HW;
        for (int i = tid; i < HW; i += 256) s += bn[i];
    }
    s = waveReduceSum(s);
    __shared__ float red[4];
    int lane = tid & 63, wave = tid >> 6;
    if (lane == 0) red[wave] = s;
    __syncthreads();
    if (tid == 0) mu[c] = (red[0] + red[1] + red[2] + red[3]) * (1.0f / 16384.0f);
}

// ---------- K2: center, L2-normalize over C, transpose to (n,p,c) bf16 ----------
#define TP 32
#define TSTRIDE 257
__global__ __launch_bounds__(256) void prep_kernel(const float* __restrict__ x,
                                                   const float* __restrict__ y,
                                                   const float* __restrict__ mu,
                                                   unsigned short* __restrict__ Xn,
                                                   unsigned short* __restrict__ Yn) {
    __shared__ float smu[C];
    __shared__ float tile[TP * TSTRIDE];
    __shared__ float red[8 * 32];
    __shared__ float invn[TP];
    int tid = threadIdx.x;
    smu[tid] = mu[tid];
    int blk = blockIdx.x;
    int n = blk >> 7;                // 128 blocks per batch
    int p0 = (blk & 127) * TP;
    int tp = tid & 31, cc = tid >> 5;
    __syncthreads();
    for (int pass = 0; pass < 2; pass++) {
        const float* in = pass ? y : x;
        unsigned short* out = pass ? Yn : Xn;
        const float* base = in + (size_t)n * C * HW + p0 + tp;
        float ssq = 0.f;
        for (int c = cc; c < C; c += 8) {
            float v = base[(size_t)c * HW] - smu[c];
            tile[tp * TSTRIDE + c] = v;
            ssq += v * v;
        }
        red[cc * 32 + tp] = ssq;
        __syncthreads();
        if (tid < 32) {
            float s = 0.f;
            for (int k = 0; k < 8; k++) s += red[k * 32 + tid];
            invn[tid] = rsqrtf(s);
        }
        __syncthreads();
        int c2 = (tid & 127) * 2;
        int pp = tid >> 7;
        for (int p = pp; p < TP; p += 2) {
            float inv = invn[p];
            unsigned short b0 = f2bf(tile[p * TSTRIDE + c2] * inv);
            unsigned short b1 = f2bf(tile[p * TSTRIDE + c2 + 1] * inv);
            unsigned int pack = (unsigned int)b0 | ((unsigned int)b1 << 16);
            ((unsigned int*)out)[(size_t)(n * HW + p0 + p) * (C / 2) + (c2 >> 1)] = pack;
        }
        __syncthreads();
    }
}

// ---------- K3: batched GEMM cos = Xn * Yn^T, bf16 out ----------
// Occupancy-first form: SINGLE 32KB stage buffer, 4 K-steps of
// {STAGE -> sync -> COMPUTE -> sync}. LDS block = 34,816 B (epilogue
// transpose is the max user) -> 4 blocks/CU (vs 2 with the 64KB double
// buffer). All latency hiding comes from 4 phase-offset blocks per CU
// (m97/m114 regime). Full-drain semantics only -- same correctness class
// as every passing round; counted-vmcnt is permanently retired here.
#define EPSTRIDE 136
// stage quarter s (K elems [s*64, s*64+64)) of A,B into the single buffer
#define STAGE(s)                                                               \
    do {                                                                       \
        unsigned short* lA = lds_us;                                           \
        unsigned short* lB = lds_us + 8192;                                    \
        _Pragma("unroll")                                                      \
        for (int t = 0; t < 4; t++) {                                          \
            int slot = t * 256 + tid;                                          \
            int r = slot >> 3, cl = slot & 7;                                  \
            int c = (s) * 8 + (cl ^ (r & 7));                                  \
            async_copy16(Ab + (size_t)r * C + c * 8, lA + slot * 8);           \
        }                                                                      \
        _Pragma("unroll")                                                      \
        for (int t = 0; t < 4; t++) {                                          \
            int slot = t * 256 + tid;                                          \
            int r = slot >> 3, cl = slot & 7;                                  \
            int c = (s) * 8 + (cl ^ (r & 7));                                  \
            async_copy16(Bb + (size_t)r * C + c * 8, lB + slot * 8);           \
        }                                                                      \
    } while (0)

#define COMPUTE()                                                              \
    do {                                                                       \
        const unsigned short* lA = lds_us;                                     \
        const unsigned short* lB = lds_us + 8192;                              \
        _Pragma("unroll")                                                      \
        for (int kkl = 0; kkl < 2; kkl++) {                                    \
            int cl4 = kkl * 4 + quad;                                          \
            int clp = cl4 ^ (mrow & 7);                                        \
            bf16x8 af[4], bfr[4];                                              \
            _Pragma("unroll")                                                  \
            for (int i = 0; i < 4; i++) {                                      \
                af[i]  = *(const bf16x8*)(lA + (wm + i * 16 + mrow) * 64 + clp * 8); \
                bfr[i] = *(const bf16x8*)(lB + (wn + i * 16 + mrow) * 64 + clp * 8); \
            }                                                                  \
            _Pragma("unroll")                                                  \
            for (int i = 0; i < 4; i++)                                        \
                _Pragma("unroll")                                              \
                for (int j = 0; j < 4; j++)                                    \
                    acc[i][j] = __builtin_amdgcn_mfma_f32_16x16x32_bf16(af[i], bfr[j], acc[i][j], 0, 0, 0); \
        }                                                                      \
    } while (0)

__global__ __launch_bounds__(256, 4) void gemm_cos(const unsigned short* __restrict__ Xn,
                                                   const unsigned short* __restrict__ Yn,
                                                   unsigned short* __restrict__ Cos) {
    __shared__ unsigned short lds_us[17408];   // 34,816 B: stage A[16KB]+B[16KB]; epilogue 128x136 bf16
    int n = blockIdx.z;
    int pBase = blockIdx.y * 128, qBase = blockIdx.x * 128;
    const unsigned short* Ab = Xn + ((size_t)n * HW + pBase) * C;
    const unsigned short* Bb = Yn + ((size_t)n * HW + qBase) * C;
    int tid = threadIdx.x, lane = tid & 63, wave = tid >> 6;
    int wm = (wave >> 1) * 64, wn = (wave & 1) * 64;
    int mrow = lane & 15, quad = lane >> 4;

    f32x4 acc[4][4];
#pragma unroll
    for (int i = 0; i < 4; i++)
#pragma unroll
        for (int j = 0; j < 4; j++) acc[i][j] = (f32x4){0.f, 0.f, 0.f, 0.f};

#pragma unroll
    for (int s = 0; s < 4; s++) {
        STAGE(s);
        __syncthreads();   // stage landed (full drain)
        COMPUTE();
        __syncthreads();   // reads retired before next overwrite / epilogue
    }

    // ---- epilogue: transpose through LDS (bf16), coalesced dwordx4 stores ----
    unsigned short* epb = lds_us;  // 128 x EPSTRIDE bf16 = 34,816 B
    int col = lane & 15, quad4 = quad * 4;
#pragma unroll
    for (int i = 0; i < 4; i++)
#pragma unroll
        for (int j = 0; j < 4; j++)
#pragma unroll
            for (int r = 0; r < 4; r++)
                epb[(wm + i * 16 + quad4 + r) * EPSTRIDE + wn + j * 16 + col] = f2bf(acc[i][j][r]);
    __syncthreads();
    unsigned short* Crow = Cos + (size_t)n * HW * HW;
#pragma unroll
    for (int it = 0; it < 8; it++) {
        int e = it * 2048 + tid * 8;
        int r = e >> 7, cg = e & 127;
        uint4 o = *(const uint4*)(epb + r * EPSTRIDE + cg);
        *(uint4*)(Crow + (size_t)(pBase + r) * HW + qBase + cg) = o;
    }
}

// ---------- K4: fused row stats + column logit-max (8 rows/block, reg-resident) ----------
__global__ __launch_bounds__(256, 3) void rowcol(const unsigned short* __restrict__ Cos,
                                                 unsigned short* __restrict__ partial) {
    int n = blockIdx.y, chunk = blockIdx.x;   // 0..511, 8 rows each
    int tid = threadIdx.x, lane = tid & 63, wave = tid >> 6;
    const unsigned short* rowbase = Cos + ((size_t)n * HW + chunk * 8) * HW;
    __shared__ float redm[8][4];
    __shared__ float sval[8][4];

    uint4 d[8][2];
#pragma unroll
    for (int r = 0; r < 8; r++) {
        const unsigned short* rp = rowbase + (size_t)r * HW;
        d[r][0] = *(const uint4*)(rp + tid * 8);
        d[r][1] = *(const uint4*)(rp + 2048 + tid * 8);
    }

    // phase 1: row maxes (batched butterfly)
    float m8[8];
#pragma unroll
    for (int r = 0; r < 8; r++) {
        float v[16];
        unpack8(d[r][0], v); unpack8(d[r][1], v + 8);
        float m = v[0];
#pragma unroll
        for (int k = 1; k < 16; k++) m = fmaxf(m, v[k]);
        m8[r] = m;
    }
#pragma unroll
    for (int off = 32; off > 0; off >>= 1)
#pragma unroll
        for (int r = 0; r < 8; r++) m8[r] = fmaxf(m8[r], __shfl_xor(m8[r], off));
    if (lane == 0)
#pragma unroll
        for (int r = 0; r < 8; r++) redm[r][wave] = m8[r];
    __syncthreads();

    float alpha[8], basec[8];
#pragma unroll
    for (int r = 0; r < 8; r++) {
        float M = fmaxf(fmaxf(redm[r][0], redm[r][1]), fmaxf(redm[r][2], redm[r][3]));
        alpha[r] = 2.0f / ((1.0f - M) + EPSF);
        basec[r] = 2.0f - alpha[r];
    }

    // phase 2: exp row-sums (batched butterfly)
    float s8[8];
#pragma unroll
    for (int r = 0; r < 8; r++) {
        float v[16];
        unpack8(d[r][0], v); unpack8(d[r][1], v + 8);
        float s = 0.f;
#pragma unroll
        for (int k = 0; k < 16; k++) s += __expf(fmaf(alpha[r], v[k], basec[r]));
        s8[r] = s;
    }
#pragma unroll
    for (int off = 32; off > 0; off >>= 1)
#pragma unroll
        for (int r = 0; r < 8; r++) s8[r] += __shfl_xor(s8[r], off);
    if (lane == 0)
#pragma unroll
        for (int r = 0; r < 8; r++) sval[r][wave] = s8[r];
    __syncthreads();

    // phase 3: beta + column logit-max
    float cmax[16];
#pragma unroll
    for (int k = 0; k < 16; k++) cmax[k] = -1e30f;
#pragma unroll
    for (int r = 0; r < 8; r++) {
        float S = sval[r][0] + sval[r][1] + sval[r][2] + sval[r][3];
        float beta = basec[r] - __logf(S);
        float v[16];
        unpack8(d[r][0], v); unpack8(d[r][1], v + 8);
#pragma unroll
        for (int k = 0; k < 16; k++) cmax[k] = fmaxf(cmax[k], fmaf(alpha[r], v[k], beta));
    }

    // store as bf16, packed uint4 (q = tid*8+k and 2048+tid*8+k)
    unsigned short* outp = partial + ((size_t)(n * 512 + chunk)) * HW;
    uint4 o0, o1;
    o0.x = (unsigned int)f2bf(cmax[0]) | ((unsigned int)f2bf(cmax[1]) << 16);
    o0.y = (unsigned int)f2bf(cmax[2]) | ((unsigned int)f2bf(cmax[3]) << 16);
    o0.z = (unsigned int)f2bf(cmax[4]) | ((unsigned int)f2bf(cmax[5]) << 16);
    o0.w = (unsigned int)f2bf(cmax[6]) | ((unsigned int)f2bf(cmax[7]) << 16);
    o1.x = (unsigned int)f2bf(cmax[8]) | ((unsigned int)f2bf(cmax[9]) << 16);
    o1.y = (unsigned int)f2bf(cmax[10]) | ((unsigned int)f2bf(cmax[11]) << 16);
    o1.z = (unsigned int)f2bf(cmax[12]) | ((unsigned int)f2bf(cmax[13]) << 16);
    o1.w = (unsigned int)f2bf(cmax[14]) | ((unsigned int)f2bf(cmax[15]) << 16);
    *(uint4*)(outp + tid * 8) = o0;
    *(uint4*)(outp + 2048 + tid * 8) = o1;
}

// ---------- K5: fused column max over all 512 chunks + exp + sum + final loss ----------
// grid (64, NB): block (g,n) owns 64 q-columns. Vectorized uint4 reads.
// Ticket-based last-block finalize; cxsum/ticket zeroed by mu_kernel.
__global__ __launch_bounds__(256) void colred(const unsigned short* __restrict__ partial,
                                              float* __restrict__ cxsum,
                                              unsigned int* __restrict__ ticket,
                                              float* __restrict__ out) {
    int n = blockIdx.y, g = blockIdx.x;
    int tid = threadIdx.x;
    int qo = tid & 7;          // q-octet within the 64-q group
    int cs = tid >> 3;         // chunk slice 0..31
    const unsigned short* p = partial + ((size_t)(n * 512 + cs)) * HW + g * 64 + qo * 8;
    float mx[8];
#pragma unroll
    for (int k = 0; k < 8; k++) mx[k] = -1e30f;
#pragma unroll 4
    for (int c = cs; c < 512; c += 32) {
        uint4 u = *(const uint4*)p;
        float v[8];
        unpack8(u, v);
#pragma unroll
        for (int k = 0; k < 8; k++) mx[k] = fmaxf(mx[k], v[k]);
        p += (size_t)32 * HW;
    }
    __shared__ float sm[32][64];
#pragma unroll
    for (int k = 0; k < 8; k++) sm[cs][qo * 8 + k] = mx[k];
    __syncthreads();
    if (tid < 64) {
        float mm = -1e30f;
#pragma unroll
        for (int s = 0; s < 32; s++) mm = fmaxf(mm, sm[s][tid]);
        float sv = __expf(mm);
        sv = waveReduceSum(sv);
        if (tid == 0) {
            atomicAdd(&cxsum[n], sv);
            __threadfence();
            unsigned int old = atomicAdd(ticket, 1u);
            if (old == (unsigned int)(64 * NB - 1)) {
                __threadfence();
                float loss = 0.f;
                for (int b = 0; b < NB; b++) {
                    float csn = atomicAdd(&cxsum[b], 0.0f);  // device-scope read of final sum
                    loss += -logf(csn * (1.0f / 4096.0f) + EPSF);
                }
                out[0] = loss * 0.25f;
            }
        }
    }
}

// ---------- launch ----------
extern "C" void kernel_launch(void* const* d_in, const int* in_sizes, int n_in,
                              void* d_out, int out_size, void* d_ws, size_t ws_size,
                              hipStream_t stream) {
    const float* x = (const float*)d_in[0];
    const float* y = (const float*)d_in[1];
    float* out = (float*)d_out;
    char* ws = (char*)d_ws;

    float* mu               = (float*)(ws + 0);                   // 1 KiB
    float* cxsum            = (float*)(ws + 1024);                // 16 B
    unsigned int* ticket    = (unsigned int*)(ws + 1040);         // 4 B
    unsigned short* Xn      = (unsigned short*)(ws + 2097152);    // 8 MiB
    unsigned short* Yn      = (unsigned short*)(ws + 10485760);   // 8 MiB
    unsigned short* partial = (unsigned short*)(ws + 2097152);    // 16 MiB bf16 (aliases Xn+Yn, used only after gemm)
    unsigned short* Cos     = (unsigned short*)(ws + 18874368);   // 128 MiB

    mu_kernel<<<C, 256, 0, stream>>>(y, mu, cxsum, ticket);
    prep_kernel<<<NROWS / TP, 256, 0, stream>>>(x, y, mu, Xn, Yn);
    gemm_cos<<<dim3(HW / 128, HW / 128, NB), 256, 0, stream>>>(Xn, Yn, Cos);
    rowcol<<<dim3(512, NB), 256, 0, stream>>>(Cos, partial);
    colred<<<dim3(64, NB), 256, 0, stream>>>(partial, cxsum, ticket, out);
}

// Round 8
// 172.884 us; speedup vs baseline: 1.2793x; 1.1394x over previous
//
#include <hip/hip_runtime.h>
#include <hip/hip_bf16.h>

// ---------- types ----------
typedef short bf16x8 __attribute__((ext_vector_type(8)));
typedef float f32x4 __attribute__((ext_vector_type(4)));

#define NB 4
#define C 256
#define HW 4096
#define NROWS (NB * HW)   // 16384
#define EPSF 1e-5f

// ---------- helpers ----------
__device__ __forceinline__ unsigned short f2bf(float f) {
    unsigned int u = __float_as_uint(f);
    unsigned int r = u + 0x7fffu + ((u >> 16) & 1u);
    return (unsigned short)(r >> 16);
}
__device__ __forceinline__ float bf2f(unsigned int h) {
    return __uint_as_float(h << 16);
}
__device__ __forceinline__ void unpack8(uint4 u, float* v) {
    unsigned int w0 = u.x, w1 = u.y, w2 = u.z, w3 = u.w;
    v[0] = bf2f(w0 & 0xffffu); v[1] = bf2f(w0 >> 16);
    v[2] = bf2f(w1 & 0xffffu); v[3] = bf2f(w1 >> 16);
    v[4] = bf2f(w2 & 0xffffu); v[5] = bf2f(w2 >> 16);
    v[6] = bf2f(w3 & 0xffffu); v[7] = bf2f(w3 >> 16);
}
__device__ __forceinline__ float waveReduceSum(float v) {
    for (int off = 32; off > 0; off >>= 1) v += __shfl_xor(v, off);
    return v;
}
// async global->LDS 16B copy; lds ptr must be wave-uniform-base + lane*16
typedef __attribute__((address_space(1))) const unsigned int glb_cu;
typedef __attribute__((address_space(3))) unsigned int lds_u;
__device__ __forceinline__ void async_copy16(const unsigned short* g, unsigned short* l) {
    __builtin_amdgcn_global_load_lds((glb_cu*)g, (lds_u*)l, 16, 0, 0);
}

// ---------- K1: per-channel partial sums of y (one block per (c,n), float4 loads) ----------
// Writes UN-normalized per-n partial sums to mup[n*C+c]; prep combines the 4.
// 1024 blocks (4/CU) + 16B/lane loads fix the old 1-block/CU latency bind.
__global__ __launch_bounds__(256) void mu_kernel(const float* __restrict__ y,
                                                 float* __restrict__ mup,
                                                 float* __restrict__ cxsum,
                                                 unsigned int* __restrict__ ticket) {
    int c = blockIdx.x, n = blockIdx.y;
    int tid = threadIdx.x;
    if (c == 0 && n == 0) {
        if (tid < NB) cxsum[tid] = 0.f;
        if (tid == NB) *ticket = 0u;
    }
    const float4* b4 = (const float4*)(y + (size_t)n * C * HW + (size_t)c * HW);
    float s = 0.f;
#pragma unroll
    for (int k = 0; k < 4; k++) {
        float4 v = b4[tid + k * 256];
        s += (v.x + v.y) + (v.z + v.w);
    }
    s = waveReduceSum(s);
    __shared__ float red[4];
    int lane = tid & 63, wave = tid >> 6;
    if (lane == 0) red[wave] = s;
    __syncthreads();
    if (tid == 0) mup[n * C + c] = (red[0] + red[1]) + (red[2] + red[3]);
}

// ---------- K2: center, L2-normalize over C, transpose to (n,p,c) bf16 ----------
// float4 loads along p: thread = (c-group cc in [0,32), p-quad tq in [0,8));
// 8 iterations x 16B replaces 32 x 4B (4x in-flight bytes per thread).
#define TP 32
#define TSTRIDE 257
__global__ __launch_bounds__(256) void prep_kernel(const float* __restrict__ x,
                                                   const float* __restrict__ y,
                                                   const float* __restrict__ mup,
                                                   unsigned short* __restrict__ Xn,
                                                   unsigned short* __restrict__ Yn) {
    __shared__ float smu[C];
    __shared__ float tile[TP * TSTRIDE];
    __shared__ float red[32 * 32];
    __shared__ float invn[TP];
    int tid = threadIdx.x;
    smu[tid] = (mup[tid] + mup[C + tid] + mup[2 * C + tid] + mup[3 * C + tid]) * (1.0f / 16384.0f);
    int blk = blockIdx.x;
    int n = blk >> 7;                // 128 blocks per batch
    int p0 = (blk & 127) * TP;
    int tq = tid & 7;                // p-quad: p = tq*4+k
    int cc = tid >> 3;               // c-group in [0,32)
    __syncthreads();
    for (int pass = 0; pass < 2; pass++) {
        const float* in = pass ? y : x;
        unsigned short* out = pass ? Yn : Xn;
        const float* base = in + (size_t)n * C * HW + p0 + tq * 4;
        float ssq0 = 0.f, ssq1 = 0.f, ssq2 = 0.f, ssq3 = 0.f;
        for (int c = cc; c < C; c += 32) {
            float4 v = *(const float4*)(base + (size_t)c * HW);
            float m = smu[c];
            v.x -= m; v.y -= m; v.z -= m; v.w -= m;
            tile[(tq * 4 + 0) * TSTRIDE + c] = v.x;
            tile[(tq * 4 + 1) * TSTRIDE + c] = v.y;
            tile[(tq * 4 + 2) * TSTRIDE + c] = v.z;
            tile[(tq * 4 + 3) * TSTRIDE + c] = v.w;
            ssq0 += v.x * v.x; ssq1 += v.y * v.y;
            ssq2 += v.z * v.z; ssq3 += v.w * v.w;
        }
        red[cc * 32 + tq * 4 + 0] = ssq0;
        red[cc * 32 + tq * 4 + 1] = ssq1;
        red[cc * 32 + tq * 4 + 2] = ssq2;
        red[cc * 32 + tq * 4 + 3] = ssq3;
        __syncthreads();
        if (tid < 32) {
            float s = 0.f;
            for (int k = 0; k < 32; k++) s += red[k * 32 + tid];
            invn[tid] = rsqrtf(s);
        }
        __syncthreads();
        int c2 = (tid & 127) * 2;
        int pp = tid >> 7;
        for (int p = pp; p < TP; p += 2) {
            float inv = invn[p];
            unsigned short b0 = f2bf(tile[p * TSTRIDE + c2] * inv);
            unsigned short b1 = f2bf(tile[p * TSTRIDE + c2 + 1] * inv);
            unsigned int pack = (unsigned int)b0 | ((unsigned int)b1 << 16);
            ((unsigned int*)out)[(size_t)(n * HW + p0 + p) * (C / 2) + (c2 >> 1)] = pack;
        }
        __syncthreads();
    }
}

// ---------- K3: batched GEMM cos = Xn * Yn^T, bf16 out ----------
// PROVEN round-7 form (46-48 us). Occupancy-first: single 32KB stage buffer,
// 4 K-steps of {STAGE -> sync -> COMPUTE -> sync}; 34,816 B LDS; 4 blocks/CU
// (VGPR-capped: 64 arch + 64 acc = 128 total). FROZEN.
#define EPSTRIDE 136
#define STAGE(s)                                                               \
    do {                                                                       \
        unsigned short* lA = lds_us;                                           \
        unsigned short* lB = lds_us + 8192;                                    \
        _Pragma("unroll")                                                      \
        for (int t = 0; t < 4; t++) {                                          \
            int slot = t * 256 + tid;                                          \
            int r = slot >> 3, cl = slot & 7;                                  \
            int c = (s) * 8 + (cl ^ (r & 7));                                  \
            async_copy16(Ab + (size_t)r * C + c * 8, lA + slot * 8);           \
        }                                                                      \
        _Pragma("unroll")                                                      \
        for (int t = 0; t < 4; t++) {                                          \
            int slot = t * 256 + tid;                                          \
            int r = slot >> 3, cl = slot & 7;                                  \
            int c = (s) * 8 + (cl ^ (r & 7));                                  \
            async_copy16(Bb + (size_t)r * C + c * 8, lB + slot * 8);           \
        }                                                                      \
    } while (0)

#define COMPUTE()                                                              \
    do {                                                                       \
        const unsigned short* lA = lds_us;                                     \
        const unsigned short* lB = lds_us + 8192;                              \
        _Pragma("unroll")                                                      \
        for (int kkl = 0; kkl < 2; kkl++) {                                    \
            int cl4 = kkl * 4 + quad;                                          \
            int clp = cl4 ^ (mrow & 7);                                        \
            bf16x8 af[4], bfr[4];                                              \
            _Pragma("unroll")                                                  \
            for (int i = 0; i < 4; i++) {                                      \
                af[i]  = *(const bf16x8*)(lA + (wm + i * 16 + mrow) * 64 + clp * 8); \
                bfr[i] = *(const bf16x8*)(lB + (wn + i * 16 + mrow) * 64 + clp * 8); \
            }                                                                  \
            _Pragma("unroll")                                                  \
            for (int i = 0; i < 4; i++)                                        \
                _Pragma("unroll")                                              \
                for (int j = 0; j < 4; j++)                                    \
                    acc[i][j] = __builtin_amdgcn_mfma_f32_16x16x32_bf16(af[i], bfr[j], acc[i][j], 0, 0, 0); \
        }                                                                      \
    } while (0)

__global__ __launch_bounds__(256, 4) void gemm_cos(const unsigned short* __restrict__ Xn,
                                                   const unsigned short* __restrict__ Yn,
                                                   unsigned short* __restrict__ Cos) {
    __shared__ unsigned short lds_us[17408];   // 34,816 B
    int n = blockIdx.z;
    int pBase = blockIdx.y * 128, qBase = blockIdx.x * 128;
    const unsigned short* Ab = Xn + ((size_t)n * HW + pBase) * C;
    const unsigned short* Bb = Yn + ((size_t)n * HW + qBase) * C;
    int tid = threadIdx.x, lane = tid & 63, wave = tid >> 6;
    int wm = (wave >> 1) * 64, wn = (wave & 1) * 64;
    int mrow = lane & 15, quad = lane >> 4;

    f32x4 acc[4][4];
#pragma unroll
    for (int i = 0; i < 4; i++)
#pragma unroll
        for (int j = 0; j < 4; j++) acc[i][j] = (f32x4){0.f, 0.f, 0.f, 0.f};

#pragma unroll
    for (int s = 0; s < 4; s++) {
        STAGE(s);
        __syncthreads();
        COMPUTE();
        __syncthreads();
    }

    // ---- epilogue: transpose through LDS (bf16), coalesced dwordx4 stores ----
    unsigned short* epb = lds_us;  // 128 x EPSTRIDE bf16 = 34,816 B
    int col = lane & 15, quad4 = quad * 4;
#pragma unroll
    for (int i = 0; i < 4; i++)
#pragma unroll
        for (int j = 0; j < 4; j++)
#pragma unroll
            for (int r = 0; r < 4; r++)
                epb[(wm + i * 16 + quad4 + r) * EPSTRIDE + wn + j * 16 + col] = f2bf(acc[i][j][r]);
    __syncthreads();
    unsigned short* Crow = Cos + (size_t)n * HW * HW;
#pragma unroll
    for (int it = 0; it < 8; it++) {
        int e = it * 2048 + tid * 8;
        int r = e >> 7, cg = e & 127;
        uint4 o = *(const uint4*)(epb + r * EPSTRIDE + cg);
        *(uint4*)(Crow + (size_t)(pBase + r) * HW + qBase + cg) = o;
    }
}

// ---------- K4: fused row stats + column logit-max (8 rows/block, reg-resident) ----------
__global__ __launch_bounds__(256, 3) void rowcol(const unsigned short* __restrict__ Cos,
                                                 unsigned short* __restrict__ partial) {
    int n = blockIdx.y, chunk = blockIdx.x;   // 0..511, 8 rows each
    int tid = threadIdx.x, lane = tid & 63, wave = tid >> 6;
    const unsigned short* rowbase = Cos + ((size_t)n * HW + chunk * 8) * HW;
    __shared__ float redm[8][4];
    __shared__ float sval[8][4];

    uint4 d[8][2];
#pragma unroll
    for (int r = 0; r < 8; r++) {
        const unsigned short* rp = rowbase + (size_t)r * HW;
        d[r][0] = *(const uint4*)(rp + tid * 8);
        d[r][1] = *(const uint4*)(rp + 2048 + tid * 8);
    }

    // phase 1: row maxes (batched butterfly)
    float m8[8];
#pragma unroll
    for (int r = 0; r < 8; r++) {
        float v[16];
        unpack8(d[r][0], v); unpack8(d[r][1], v + 8);
        float m = v[0];
#pragma unroll
        for (int k = 1; k < 16; k++) m = fmaxf(m, v[k]);
        m8[r] = m;
    }
#pragma unroll
    for (int off = 32; off > 0; off >>= 1)
#pragma unroll
        for (int r = 0; r < 8; r++) m8[r] = fmaxf(m8[r], __shfl_xor(m8[r], off));
    if (lane == 0)
#pragma unroll
        for (int r = 0; r < 8; r++) redm[r][wave] = m8[r];
    __syncthreads();

    float alpha[8], basec[8];
#pragma unroll
    for (int r = 0; r < 8; r++) {
        float M = fmaxf(fmaxf(redm[r][0], redm[r][1]), fmaxf(redm[r][2], redm[r][3]));
        alpha[r] = 2.0f / ((1.0f - M) + EPSF);
        basec[r] = 2.0f - alpha[r];
    }

    // phase 2: exp row-sums (batched butterfly)
    float s8[8];
#pragma unroll
    for (int r = 0; r < 8; r++) {
        float v[16];
        unpack8(d[r][0], v); unpack8(d[r][1], v + 8);
        float s = 0.f;
#pragma unroll
        for (int k = 0; k < 16; k++) s += __expf(fmaf(alpha[r], v[k], basec[r]));
        s8[r] = s;
    }
#pragma unroll
    for (int off = 32; off > 0; off >>= 1)
#pragma unroll
        for (int r = 0; r < 8; r++) s8[r] += __shfl_xor(s8[r], off);
    if (lane == 0)
#pragma unroll
        for (int r = 0; r < 8; r++) sval[r][wave] = s8[r];
    __syncthreads();

    // phase 3: beta + column logit-max
    float cmax[16];
#pragma unroll
    for (int k = 0; k < 16; k++) cmax[k] = -1e30f;
#pragma unroll
    for (int r = 0; r < 8; r++) {
        float S = sval[r][0] + sval[r][1] + sval[r][2] + sval[r][3];
        float beta = basec[r] - __logf(S);
        float v[16];
        unpack8(d[r][0], v); unpack8(d[r][1], v + 8);
#pragma unroll
        for (int k = 0; k < 16; k++) cmax[k] = fmaxf(cmax[k], fmaf(alpha[r], v[k], beta));
    }

    // store as bf16, packed uint4 (q = tid*8+k and 2048+tid*8+k)
    unsigned short* outp = partial + ((size_t)(n * 512 + chunk)) * HW;
    uint4 o0, o1;
    o0.x = (unsigned int)f2bf(cmax[0]) | ((unsigned int)f2bf(cmax[1]) << 16);
    o0.y = (unsigned int)f2bf(cmax[2]) | ((unsigned int)f2bf(cmax[3]) << 16);
    o0.z = (unsigned int)f2bf(cmax[4]) | ((unsigned int)f2bf(cmax[5]) << 16);
    o0.w = (unsigned int)f2bf(cmax[6]) | ((unsigned int)f2bf(cmax[7]) << 16);
    o1.x = (unsigned int)f2bf(cmax[8]) | ((unsigned int)f2bf(cmax[9]) << 16);
    o1.y = (unsigned int)f2bf(cmax[10]) | ((unsigned int)f2bf(cmax[11]) << 16);
    o1.z = (unsigned int)f2bf(cmax[12]) | ((unsigned int)f2bf(cmax[13]) << 16);
    o1.w = (unsigned int)f2bf(cmax[14]) | ((unsigned int)f2bf(cmax[15]) << 16);
    *(uint4*)(outp + tid * 8) = o0;
    *(uint4*)(outp + 2048 + tid * 8) = o1;
}

// ---------- K5: fused column max over all 512 chunks + exp + sum + final loss ----------
// grid (128, NB) = 512 blocks (2/CU); block owns 32 q-columns; thread =
// (q-octet qo in [0,4), chunk-slice cs in [0,64)). 32-lane shuffle reduce.
__global__ __launch_bounds__(256) void colred(const unsigned short* __restrict__ partial,
                                              float* __restrict__ cxsum,
                                              unsigned int* __restrict__ ticket,
                                              float* __restrict__ out) {
    int n = blockIdx.y, g = blockIdx.x;
    int tid = threadIdx.x;
    int qo = tid & 3;          // q-octet within the 32-q group
    int cs = tid >> 2;         // chunk slice 0..63
    const unsigned short* p = partial + ((size_t)(n * 512 + cs)) * HW + g * 32 + qo * 8;
    float mx[8];
#pragma unroll
    for (int k = 0; k < 8; k++) mx[k] = -1e30f;
#pragma unroll 4
    for (int c = cs; c < 512; c += 64) {
        uint4 u = *(const uint4*)p;
        float v[8];
        unpack8(u, v);
#pragma unroll
        for (int k = 0; k < 8; k++) mx[k] = fmaxf(mx[k], v[k]);
        p += (size_t)64 * HW;
    }
    __shared__ float sm[64][32];
#pragma unroll
    for (int k = 0; k < 8; k++) sm[cs][qo * 8 + k] = mx[k];
    __syncthreads();
    if (tid < 32) {            // lanes 0..31 of wave 0 (all active for shuffles)
        float mm = -1e30f;
#pragma unroll
        for (int s = 0; s < 64; s++) mm = fmaxf(mm, sm[s][tid]);
        float sv = __expf(mm);
#pragma unroll
        for (int off = 16; off > 0; off >>= 1) sv += __shfl_xor(sv, off);
        if (tid == 0) {
            atomicAdd(&cxsum[n], sv);
            __threadfence();
            unsigned int old = atomicAdd(ticket, 1u);
            if (old == (unsigned int)(128 * NB - 1)) {
                __threadfence();
                float loss = 0.f;
                for (int b = 0; b < NB; b++) {
                    float csn = atomicAdd(&cxsum[b], 0.0f);  // device-scope read of final sum
                    loss += -logf(csn * (1.0f / 4096.0f) + EPSF);
                }
                out[0] = loss * 0.25f;
            }
        }
    }
}

// ---------- launch ----------
extern "C" void kernel_launch(void* const* d_in, const int* in_sizes, int n_in,
                              void* d_out, int out_size, void* d_ws, size_t ws_size,
                              hipStream_t stream) {
    const float* x = (const float*)d_in[0];
    const float* y = (const float*)d_in[1];
    float* out = (float*)d_out;
    char* ws = (char*)d_ws;

    float* mup              = (float*)(ws + 0);                   // 4 KiB (NB x C partial sums)
    float* cxsum            = (float*)(ws + 8192);                // 16 B
    unsigned int* ticket    = (unsigned int*)(ws + 8208);         // 4 B
    unsigned short* Xn      = (unsigned short*)(ws + 2097152);    // 8 MiB
    unsigned short* Yn      = (unsigned short*)(ws + 10485760);   // 8 MiB
    unsigned short* partial = (unsigned short*)(ws + 2097152);    // 16 MiB bf16 (aliases Xn+Yn, used only after gemm)
    unsigned short* Cos     = (unsigned short*)(ws + 18874368);   // 128 MiB

    mu_kernel<<<dim3(C, NB), 256, 0, stream>>>(y, mup, cxsum, ticket);
    prep_kernel<<<NROWS / TP, 256, 0, stream>>>(x, y, mup, Xn, Yn);
    gemm_cos<<<dim3(HW / 128, HW / 128, NB), 256, 0, stream>>>(Xn, Yn, Cos);
    rowcol<<<dim3(512, NB), 256, 0, stream>>>(Cos, partial);
    colred<<<dim3(128, NB), 256, 0, stream>>>(partial, cxsum, ticket, out);
}